// Round 2
// baseline (1051.101 us; speedup 1.0000x reference)
//
#include <hip/hip_runtime.h>
#include <hip/hip_bf16.h>

// DeeperGCN (GENConv softmax-agg) on MI355X.
// Strategy: build CSR by dst once per launch, then per layer:
//   ln_relu (layers 1-3) -> conv (online softmax, wave-per-node, lane=channel)
//   -> mlp (64->128 LN ReLU ->64, LDS-staged packed weights) with fused residual.

static __device__ __forceinline__ float wave_sum(float v) {
    #pragma unroll
    for (int o = 32; o; o >>= 1) v += __shfl_xor(v, o);
    return v;
}

__global__ void zero_ints_k(int* __restrict__ p, int n) {
    int g = blockIdx.x * blockDim.x + threadIdx.x;
    if (g < n) p[g] = 0;
}

__global__ void hist_k(const int* __restrict__ dst, int* __restrict__ deg, int e) {
    int g = blockIdx.x * blockDim.x + threadIdx.x;
    if (g < e) atomicAdd(&deg[dst[g]], 1);
}

__global__ __launch_bounds__(1024) void scan_block_k(const int* __restrict__ in,
                                                     int* __restrict__ outPart,
                                                     int* __restrict__ bsum, int n) {
    __shared__ int s[1024];
    int t = threadIdx.x;
    int g = blockIdx.x * 1024 + t;
    int v = (g < n) ? in[g] : 0;
    s[t] = v;
    __syncthreads();
    for (int o = 1; o < 1024; o <<= 1) {
        int add = (t >= o) ? s[t - o] : 0;
        __syncthreads();
        s[t] += add;
        __syncthreads();
    }
    if (g < n) outPart[g] = s[t] - v;   // exclusive within block
    if (t == 1023) bsum[blockIdx.x] = s[t];
}

__global__ void scan_tops_k(const int* __restrict__ bsum, int* __restrict__ bbase, int nb) {
    if (threadIdx.x == 0 && blockIdx.x == 0) {
        int a = 0;
        for (int i = 0; i < nb; i++) { bbase[i] = a; a += bsum[i]; }
    }
}

__global__ void add_base_k(int* __restrict__ offs, int* __restrict__ woff,
                           const int* __restrict__ bbase, int n) {
    int g = blockIdx.x * blockDim.x + threadIdx.x;
    if (g < n) { int v = offs[g] + bbase[g >> 10]; offs[g] = v; woff[g] = v; }
}

__global__ void csr_fill_k(const int* __restrict__ src, const int* __restrict__ dst,
                           int* __restrict__ woff, int* __restrict__ csr, int e) {
    int g = blockIdx.x * blockDim.x + threadIdx.x;
    if (g < e) {
        int slot = atomicAdd(&woff[dst[g]], 1);
        csr[slot] = src[g];
    }
}

// GENConv softmax aggregation: one wave per node, lane = channel.
// Online softmax over in-edges: agg = sum(msg*exp(w-m)) / (sum(exp(w-m)) + 1e-16)
// out = agg + h  (root add)
__global__ __launch_bounds__(256) void conv_k(const float* __restrict__ h,
                                              const int* __restrict__ offs,
                                              const int* __restrict__ deg,
                                              const int* __restrict__ csr,
                                              const float* __restrict__ tptr,
                                              float* __restrict__ out, int n) {
    int wid = threadIdx.x >> 6, lane = threadIdx.x & 63;
    int node = blockIdx.x * 4 + wid;
    if (node >= n) return;
    float tt = tptr[0];
    int start = offs[node], d = deg[node];
    float m = -__builtin_huge_valf(), num = 0.f, den = 0.f;
    for (int i = 0; i < d; i++) {
        int s = csr[start + i];
        float v = h[(size_t)s * 64 + lane];
        float msg = fmaxf(v, 0.f) + 1e-7f;
        float w = msg * tt;
        float nm = fmaxf(m, w);
        float sc = __expf(m - nm);   // m=-inf first iter -> exp(-inf)=0, no NaN
        float p = __expf(w - nm);
        num = num * sc + msg * p;
        den = den * sc + p;
        m = nm;
    }
    float agg = num / (den + 1e-16f);
    out[(size_t)node * 64 + lane] = agg + h[(size_t)node * 64 + lane];
}

__global__ __launch_bounds__(256) void ln_relu_k(const float* __restrict__ x,
                                                 const float* __restrict__ g,
                                                 const float* __restrict__ b,
                                                 float* __restrict__ out, int n) {
    int wid = threadIdx.x >> 6, lane = threadIdx.x & 63;
    int node = blockIdx.x * 4 + wid;
    if (node >= n) return;
    float v = x[(size_t)node * 64 + lane];
    float mu = wave_sum(v) * (1.f / 64.f);
    float d = v - mu;
    float var = wave_sum(d * d) * (1.f / 64.f);
    float r = d * rsqrtf(var + 1e-5f);
    out[(size_t)node * 64 + lane] = fmaxf(r * g[lane] + b[lane], 0.f);
}

// MLP: h1 = in @ W1^T + b1 (128); relu(LN(h1, mg, mb)); out = r @ W2^T + b2 (+residual)
// Wave-per-node; W1 packed as float2 per (k,lane) = (W1[lane][k], W1[lane+64][k]);
// W2 packed as float2 per (j2,lane) = (W2[lane][2j2], W2[lane][2j2+1]).
template <int RES>
__global__ __launch_bounds__(256) void mlp_k(const float* __restrict__ in,
                                             const float* __restrict__ W1,
                                             const float* __restrict__ b1,
                                             const float* __restrict__ mg,
                                             const float* __restrict__ mb,
                                             const float* __restrict__ W2,
                                             const float* __restrict__ b2,
                                             float* __restrict__ xio, int n) {
    __shared__ float2 w1p[64 * 64];
    __shared__ float2 w2p[64 * 64];
    __shared__ float sb1[128], smg[128], smb[128], sb2[64];
    __shared__ float zbuf[4][64];
    __shared__ float rbuf[4][128];

    for (int i = threadIdx.x; i < 4096; i += 256) {
        int l = i >> 6, k = i & 63;                     // coalesced global reads over k
        w1p[k * 64 + l] = make_float2(W1[l * 64 + k], W1[(l + 64) * 64 + k]);
    }
    const float2* W2v = (const float2*)W2;
    for (int i = threadIdx.x; i < 4096; i += 256) {
        int c = i >> 6, j2 = i & 63;                    // coalesced float2 reads over j2
        w2p[j2 * 64 + c] = W2v[c * 64 + j2];
    }
    for (int i = threadIdx.x; i < 128; i += 256) { sb1[i] = b1[i]; smg[i] = mg[i]; smb[i] = mb[i]; }
    if (threadIdx.x < 64) sb2[threadIdx.x] = b2[threadIdx.x];
    __syncthreads();

    int wid = threadIdx.x >> 6, lane = threadIdx.x & 63;
    int base = blockIdx.x * 64;
    int lim = min(base + 64, n);
    for (int node = base + wid; node < lim; node += 4) {
        float z = in[(size_t)node * 64 + lane];
        zbuf[wid][lane] = z;
        float ha = sb1[lane], hb = sb1[lane + 64];
        #pragma unroll 8
        for (int k = 0; k < 64; k++) {
            float zk = zbuf[wid][k];                    // LDS broadcast
            float2 w = w1p[k * 64 + lane];              // conflict-free b64
            ha += w.x * zk; hb += w.y * zk;
        }
        float mu = wave_sum(ha + hb) * (1.f / 128.f);
        float da = ha - mu, db = hb - mu;
        float rstd = rsqrtf(wave_sum(da * da + db * db) * (1.f / 128.f) + 1e-5f);
        float ra = fmaxf(da * rstd * smg[lane] + smb[lane], 0.f);
        float rb = fmaxf(db * rstd * smg[lane + 64] + smb[lane + 64], 0.f);
        rbuf[wid][lane] = ra; rbuf[wid][lane + 64] = rb;  // same-wave LDS, no barrier
        float2* rv = (float2*)rbuf[wid];
        float acc = sb2[lane];
        #pragma unroll 8
        for (int j2 = 0; j2 < 64; j2++) {
            float2 r2 = rv[j2];                         // LDS broadcast
            float2 w = w2p[j2 * 64 + lane];             // conflict-free b64
            acc += r2.x * w.x + r2.y * w.y;
        }
        if (RES) acc += xio[(size_t)node * 64 + lane];
        xio[(size_t)node * 64 + lane] = acc;
    }
}

extern "C" void kernel_launch(void* const* d_in, const int* in_sizes, int n_in,
                              void* d_out, int out_size, void* d_ws, size_t ws_size,
                              hipStream_t stream) {
    const float* x   = (const float*)d_in[0];
    const int*   ei  = (const int*)d_in[1];
    const float* t   = (const float*)d_in[2];
    const float* W1  = (const float*)d_in[3];
    const float* b1  = (const float*)d_in[4];
    const float* mg  = (const float*)d_in[5];
    const float* mb  = (const float*)d_in[6];
    const float* W2  = (const float*)d_in[7];
    const float* b2  = (const float*)d_in[8];
    const float* lng = (const float*)d_in[9];
    const float* lnb = (const float*)d_in[10];

    int n = in_sizes[0] / 64;
    int e = in_sizes[1] / 2;
    int L = in_sizes[2];
    const int* src = ei;
    const int* dst = ei + e;

    char* ws = (char*)d_ws;
    size_t off = 0;
    auto alloc = [&](size_t bytes) -> void* {
        void* p = ws + off;
        off = (off + bytes + 255) & ~(size_t)255;
        return p;
    };
    int*   deg   = (int*)alloc((size_t)n * 4);
    int*   offs  = (int*)alloc((size_t)n * 4);
    int*   woff  = (int*)alloc((size_t)n * 4);
    int*   bsum  = (int*)alloc(256 * 4);
    int*   bbase = (int*)alloc(256 * 4);
    int*   csr   = (int*)alloc((size_t)e * 4);
    float* xcur  = (float*)alloc((size_t)n * 64 * 4);
    float* hin   = (float*)alloc((size_t)n * 64 * 4);
    float* tmp   = (float*)alloc((size_t)n * 64 * 4);

    int nb = (n + 1023) / 1024;
    zero_ints_k<<<(n + 255) / 256, 256, 0, stream>>>(deg, n);
    hist_k<<<(e + 255) / 256, 256, 0, stream>>>(dst, deg, e);
    scan_block_k<<<nb, 1024, 0, stream>>>(deg, offs, bsum, n);
    scan_tops_k<<<1, 64, 0, stream>>>(bsum, bbase, nb);
    add_base_k<<<(n + 255) / 256, 256, 0, stream>>>(offs, woff, bbase, n);
    csr_fill_k<<<(e + 255) / 256, 256, 0, stream>>>(src, dst, woff, csr, e);

    int nodeBlocks = (n + 3) / 4;
    int mlpBlocks = (n + 63) / 64;

    // layer 0: x = mlp(conv(x))  (no residual)
    conv_k<<<nodeBlocks, 256, 0, stream>>>(x, offs, deg, csr, t + 0, tmp, n);
    mlp_k<0><<<mlpBlocks, 256, 0, stream>>>(tmp, W1, b1, mg, mb, W2, b2, xcur, n);

    // layers 1..L-1: x = x + mlp(conv(relu(LN(x))))
    for (int i = 1; i < L; i++) {
        ln_relu_k<<<nodeBlocks, 256, 0, stream>>>(xcur, lng + i * 64, lnb + i * 64, hin, n);
        conv_k<<<nodeBlocks, 256, 0, stream>>>(hin, offs, deg, csr, t + i, tmp, n);
        mlp_k<1><<<mlpBlocks, 256, 0, stream>>>(tmp, W1 + (size_t)i * 8192, b1 + i * 128,
                                                mg + i * 128, mb + i * 128,
                                                W2 + (size_t)i * 8192, b2 + i * 64, xcur, n);
    }

    // final: relu(LN(x, lng[0], lnb[0])) -> d_out
    ln_relu_k<<<nodeBlocks, 256, 0, stream>>>(xcur, lng, lnb, (float*)d_out, n);
}

// Round 5
// 659.802 us; speedup vs baseline: 1.5931x; 1.5931x over previous
//
#include <hip/hip_runtime.h>
#include <hip/hip_bf16.h>

// DeeperGCN (GENConv softmax-agg) on MI355X.
// R4: register-weight MLP split (R3, unmeasured) + conv 4-edge pipelined unroll.
// CSR built per launch.

static __device__ __forceinline__ float wave_sum(float v) {
    #pragma unroll
    for (int o = 32; o; o >>= 1) v += __shfl_xor(v, o);
    return v;
}

__global__ void zero_ints_k(int* __restrict__ p, int n) {
    int g = blockIdx.x * blockDim.x + threadIdx.x;
    if (g < n) p[g] = 0;
}

__global__ void hist_k(const int* __restrict__ dst, int* __restrict__ deg, int e) {
    int g = blockIdx.x * blockDim.x + threadIdx.x;
    if (g < e) atomicAdd(&deg[dst[g]], 1);
}

__global__ __launch_bounds__(1024) void scan_block_k(const int* __restrict__ in,
                                                     int* __restrict__ outPart,
                                                     int* __restrict__ bsum, int n) {
    __shared__ int s[1024];
    int t = threadIdx.x;
    int g = blockIdx.x * 1024 + t;
    int v = (g < n) ? in[g] : 0;
    s[t] = v;
    __syncthreads();
    for (int o = 1; o < 1024; o <<= 1) {
        int add = (t >= o) ? s[t - o] : 0;
        __syncthreads();
        s[t] += add;
        __syncthreads();
    }
    if (g < n) outPart[g] = s[t] - v;   // exclusive within block
    if (t == 1023) bsum[blockIdx.x] = s[t];
}

__global__ void scan_tops_k(const int* __restrict__ bsum, int* __restrict__ bbase, int nb) {
    if (threadIdx.x == 0 && blockIdx.x == 0) {
        int a = 0;
        for (int i = 0; i < nb; i++) { bbase[i] = a; a += bsum[i]; }
    }
}

__global__ void add_base_k(int* __restrict__ offs, int* __restrict__ woff,
                           const int* __restrict__ bbase, int n) {
    int g = blockIdx.x * blockDim.x + threadIdx.x;
    if (g < n) { int v = offs[g] + bbase[g >> 10]; offs[g] = v; woff[g] = v; }
}

__global__ void csr_fill_k(const int* __restrict__ src, const int* __restrict__ dst,
                           int* __restrict__ woff, int* __restrict__ csr, int e) {
    int g = blockIdx.x * blockDim.x + threadIdx.x;
    if (g < e) {
        int slot = atomicAdd(&woff[dst[g]], 1);
        csr[slot] = src[g];
    }
}

// GENConv softmax aggregation: one wave per node, lane = channel.
// Online softmax, 4-edge pipelined unroll: 4 index loads then 4 gathers in
// flight per wave to cover the dependent-load latency chain.
__global__ __launch_bounds__(256) void conv_k(const float* __restrict__ h,
                                              const int* __restrict__ offs,
                                              const int* __restrict__ deg,
                                              const int* __restrict__ csr,
                                              const float* __restrict__ tptr,
                                              float* __restrict__ out, int n) {
    int wid = threadIdx.x >> 6, lane = threadIdx.x & 63;
    int node = blockIdx.x * 4 + wid;
    if (node >= n) return;
    float tt = tptr[0];
    int start = offs[node], d = deg[node];
    float m = -__builtin_huge_valf(), num = 0.f, den = 0.f;
    int i = 0;
    for (; i + 4 <= d; i += 4) {
        int s0 = csr[start + i];
        int s1 = csr[start + i + 1];
        int s2 = csr[start + i + 2];
        int s3 = csr[start + i + 3];
        float v0 = h[(size_t)s0 * 64 + lane];
        float v1 = h[(size_t)s1 * 64 + lane];
        float v2 = h[(size_t)s2 * 64 + lane];
        float v3 = h[(size_t)s3 * 64 + lane];
        float msg0 = fmaxf(v0, 0.f) + 1e-7f;
        float msg1 = fmaxf(v1, 0.f) + 1e-7f;
        float msg2 = fmaxf(v2, 0.f) + 1e-7f;
        float msg3 = fmaxf(v3, 0.f) + 1e-7f;
        float w0 = msg0 * tt, w1 = msg1 * tt, w2 = msg2 * tt, w3 = msg3 * tt;
        float nm = fmaxf(fmaxf(m, fmaxf(w0, w1)), fmaxf(w2, w3));
        float sc = __expf(m - nm);
        float p0 = __expf(w0 - nm);
        float p1 = __expf(w1 - nm);
        float p2 = __expf(w2 - nm);
        float p3 = __expf(w3 - nm);
        num = num * sc + (msg0 * p0 + msg1 * p1) + (msg2 * p2 + msg3 * p3);
        den = den * sc + (p0 + p1) + (p2 + p3);
        m = nm;
    }
    for (; i < d; i++) {
        int s0 = csr[start + i];
        float v0 = h[(size_t)s0 * 64 + lane];
        float msg0 = fmaxf(v0, 0.f) + 1e-7f;
        float w0 = msg0 * tt;
        float nm = fmaxf(m, w0);
        float sc = __expf(m - nm);
        float p0 = __expf(w0 - nm);
        num = num * sc + msg0 * p0;
        den = den * sc + p0;
        m = nm;
    }
    float agg = num / (den + 1e-16f);
    out[(size_t)node * 64 + lane] = agg + h[(size_t)node * 64 + lane];
}

__global__ __launch_bounds__(256) void ln_relu_k(const float* __restrict__ x,
                                                 const float* __restrict__ g,
                                                 const float* __restrict__ b,
                                                 float* __restrict__ out, int n) {
    int wid = threadIdx.x >> 6, lane = threadIdx.x & 63;
    int node = blockIdx.x * 4 + wid;
    if (node >= n) return;
    float v = x[(size_t)node * 64 + lane];
    float mu = wave_sum(v) * (1.f / 64.f);
    float d = v - mu;
    float var = wave_sum(d * d) * (1.f / 64.f);
    float r = d * rsqrtf(var + 1e-5f);
    out[(size_t)node * 64 + lane] = fmaxf(r * g[lane] + b[lane], 0.f);
}

// GEMM1 + LN + ReLU: r[node,0:128] = relu(LN(in[node,:] @ W1^T + b1))
// Lane owns output channels (lane, lane+64); W1 rows register-resident.
// LDS traffic: per-node z stage (conflict-free write) + uniform b128 broadcasts.
__global__ __launch_bounds__(256, 2) void mlp1_k(const float* __restrict__ in,
                                                 const float* __restrict__ W1,
                                                 const float* __restrict__ b1,
                                                 const float* __restrict__ mg,
                                                 const float* __restrict__ mb,
                                                 float* __restrict__ r, int n) {
    __shared__ float zs[4][64];
    int wid = threadIdx.x >> 6, lane = threadIdx.x & 63;

    const float4* W1v = (const float4*)W1;
    float4 wa[16], wb[16];
    #pragma unroll
    for (int q = 0; q < 16; q++) {
        wa[q] = W1v[lane * 16 + q];          // row `lane`   of W1 [128][64]
        wb[q] = W1v[(lane + 64) * 16 + q];   // row `lane+64`
    }
    float ba = b1[lane], bb = b1[lane + 64];
    float ga = mg[lane], gb = mg[lane + 64];
    float ca = mb[lane], cb = mb[lane + 64];

    for (int node = blockIdx.x * 4 + wid; node < n; node += gridDim.x * 4) {
        zs[wid][lane] = in[(size_t)node * 64 + lane];
        const float4* z4 = (const float4*)zs[wid];
        float ha = ba, hb = bb;
        #pragma unroll
        for (int q = 0; q < 16; q++) {
            float4 z = z4[q];                 // uniform-address broadcast read
            ha += wa[q].x * z.x + wa[q].y * z.y + wa[q].z * z.z + wa[q].w * z.w;
            hb += wb[q].x * z.x + wb[q].y * z.y + wb[q].z * z.z + wb[q].w * z.w;
        }
        float mu = wave_sum(ha + hb) * (1.f / 128.f);
        float da = ha - mu, db = hb - mu;
        float rstd = rsqrtf(wave_sum(da * da + db * db) * (1.f / 128.f) + 1e-5f);
        float ra = fmaxf(da * rstd * ga + ca, 0.f);
        float rb = fmaxf(db * rstd * gb + cb, 0.f);
        r[(size_t)node * 128 + lane] = ra;
        r[(size_t)node * 128 + 64 + lane] = rb;
    }
}

// GEMM2 (+bias, +optional residual): xout[node,lane] = r[node,:] @ W2[lane,:] + b2 (+xout)
// Lane owns output channel `lane`; W2 row (128 f32) register-resident.
template <int RES>
__global__ __launch_bounds__(256, 2) void mlp2_k(const float* __restrict__ r,
                                                 const float* __restrict__ W2,
                                                 const float* __restrict__ b2,
                                                 float* __restrict__ xio, int n) {
    __shared__ float rs[4][128];
    int wid = threadIdx.x >> 6, lane = threadIdx.x & 63;

    const float4* W2v = (const float4*)W2;
    float4 w[32];
    #pragma unroll
    for (int q = 0; q < 32; q++) w[q] = W2v[lane * 32 + q];   // row `lane` of W2 [64][128]
    float bz = b2[lane];

    for (int node = blockIdx.x * 4 + wid; node < n; node += gridDim.x * 4) {
        rs[wid][lane] = r[(size_t)node * 128 + lane];
        rs[wid][64 + lane] = r[(size_t)node * 128 + 64 + lane];
        const float4* r4 = (const float4*)rs[wid];
        float acc = bz;
        #pragma unroll
        for (int q = 0; q < 32; q++) {
            float4 v = r4[q];                 // uniform-address broadcast read
            acc += w[q].x * v.x + w[q].y * v.y + w[q].z * v.z + w[q].w * v.w;
        }
        if (RES) acc += xio[(size_t)node * 64 + lane];
        xio[(size_t)node * 64 + lane] = acc;
    }
}

extern "C" void kernel_launch(void* const* d_in, const int* in_sizes, int n_in,
                              void* d_out, int out_size, void* d_ws, size_t ws_size,
                              hipStream_t stream) {
    const float* x   = (const float*)d_in[0];
    const int*   ei  = (const int*)d_in[1];
    const float* t   = (const float*)d_in[2];
    const float* W1  = (const float*)d_in[3];
    const float* b1  = (const float*)d_in[4];
    const float* mg  = (const float*)d_in[5];
    const float* mb  = (const float*)d_in[6];
    const float* W2  = (const float*)d_in[7];
    const float* b2  = (const float*)d_in[8];
    const float* lng = (const float*)d_in[9];
    const float* lnb = (const float*)d_in[10];

    int n = in_sizes[0] / 64;
    int e = in_sizes[1] / 2;
    int L = in_sizes[2];
    const int* src = ei;
    const int* dst = ei + e;

    char* ws = (char*)d_ws;
    size_t off = 0;
    auto alloc = [&](size_t bytes) -> void* {
        void* p = ws + off;
        off = (off + bytes + 255) & ~(size_t)255;
        return p;
    };
    int*   deg   = (int*)alloc((size_t)n * 4);
    int*   offs  = (int*)alloc((size_t)n * 4);
    int*   woff  = (int*)alloc((size_t)n * 4);
    int*   bsum  = (int*)alloc(256 * 4);
    int*   bbase = (int*)alloc(256 * 4);
    int*   csr   = (int*)alloc((size_t)e * 4);
    float* xcur  = (float*)alloc((size_t)n * 64 * 4);
    float* hin   = (float*)alloc((size_t)n * 64 * 4);
    float* tmp   = (float*)alloc((size_t)n * 64 * 4);
    float* rbuf  = (float*)alloc((size_t)n * 128 * 4);

    int nb = (n + 1023) / 1024;
    zero_ints_k<<<(n + 255) / 256, 256, 0, stream>>>(deg, n);
    hist_k<<<(e + 255) / 256, 256, 0, stream>>>(dst, deg, e);
    scan_block_k<<<nb, 1024, 0, stream>>>(deg, offs, bsum, n);
    scan_tops_k<<<1, 64, 0, stream>>>(bsum, bbase, nb);
    add_base_k<<<(n + 255) / 256, 256, 0, stream>>>(offs, woff, bbase, n);
    csr_fill_k<<<(e + 255) / 256, 256, 0, stream>>>(src, dst, woff, csr, e);

    int nodeBlocks = (n + 3) / 4;
    const int mlpGrid = 512;   // 2 blocks/CU at ~170 VGPR; ~24 nodes/wave amortizes reg-weight load

    // layer 0: x = mlp(conv(x))  (no residual)
    conv_k<<<nodeBlocks, 256, 0, stream>>>(x, offs, deg, csr, t + 0, tmp, n);
    mlp1_k<<<mlpGrid, 256, 0, stream>>>(tmp, W1, b1, mg, mb, rbuf, n);
    mlp2_k<0><<<mlpGrid, 256, 0, stream>>>(rbuf, W2, b2, xcur, n);

    // layers 1..L-1: x = x + mlp(conv(relu(LN(x))))
    for (int i = 1; i < L; i++) {
        ln_relu_k<<<nodeBlocks, 256, 0, stream>>>(xcur, lng + i * 64, lnb + i * 64, hin, n);
        conv_k<<<nodeBlocks, 256, 0, stream>>>(hin, offs, deg, csr, t + i, tmp, n);
        mlp1_k<<<mlpGrid, 256, 0, stream>>>(tmp, W1 + (size_t)i * 8192, b1 + i * 128,
                                            mg + i * 128, mb + i * 128, rbuf, n);
        mlp2_k<1><<<mlpGrid, 256, 0, stream>>>(rbuf, W2 + (size_t)i * 8192, b2 + i * 64, xcur, n);
    }

    // final: relu(LN(x, lng[0], lnb[0])) -> d_out
    ln_relu_k<<<nodeBlocks, 256, 0, stream>>>(xcur, lng, lnb, (float*)d_out, n);
}

// Round 6
// 602.412 us; speedup vs baseline: 1.7448x; 1.0953x over previous
//
#include <hip/hip_runtime.h>
#include <hip/hip_bf16.h>

// DeeperGCN (GENConv softmax-agg) on MI355X.
// R6: CSR fill via 2-pass bucketed scatter (kills 64B-line write amplification
// seen in R5: csr_fill WRITE_SIZE=51.7MB for 3.2MB of data). Conv 8-unrolled.

static __device__ __forceinline__ float wave_sum(float v) {
    #pragma unroll
    for (int o = 32; o; o >>= 1) v += __shfl_xor(v, o);
    return v;
}

__global__ void zero_ints_k(int* __restrict__ p, int n) {
    int g = blockIdx.x * blockDim.x + threadIdx.x;
    if (g < n) p[g] = 0;
}

__global__ void hist_k(const int* __restrict__ dst, int* __restrict__ deg, int e) {
    int g = blockIdx.x * blockDim.x + threadIdx.x;
    if (g < e) atomicAdd(&deg[dst[g]], 1);
}

__global__ __launch_bounds__(1024) void scan_block_k(const int* __restrict__ in,
                                                     int* __restrict__ outPart,
                                                     int* __restrict__ bsum, int n) {
    __shared__ int s[1024];
    int t = threadIdx.x;
    int g = blockIdx.x * 1024 + t;
    int v = (g < n) ? in[g] : 0;
    s[t] = v;
    __syncthreads();
    for (int o = 1; o < 1024; o <<= 1) {
        int add = (t >= o) ? s[t - o] : 0;
        __syncthreads();
        s[t] += add;
        __syncthreads();
    }
    if (g < n) outPart[g] = s[t] - v;   // exclusive within block
    if (t == 1023) bsum[blockIdx.x] = s[t];
}

__global__ void scan_tops_k(const int* __restrict__ bsum, int* __restrict__ bbase, int nb) {
    if (threadIdx.x == 0 && blockIdx.x == 0) {
        int a = 0;
        for (int i = 0; i < nb; i++) { bbase[i] = a; a += bsum[i]; }
    }
}

__global__ void add_base_k(int* __restrict__ offs, const int* __restrict__ bbase, int n) {
    int g = blockIdx.x * blockDim.x + threadIdx.x;
    if (g < n) offs[g] += bbase[g >> 10];
}

// Pass 1: block takes 4096 contiguous edges, ranks per 128-node bucket via LDS
// atomics, reserves per-bucket global ranges (512 global atomics/block), appends
// (src,dst) into per-bucket staging. Block-local runs ~84B -> line-local writes.
#define EPB 4096
#define BCAP 4096
__global__ __launch_bounds__(256) void bucket_scatter_k(const int* __restrict__ src,
                                                        const int* __restrict__ dst,
                                                        int* __restrict__ bcnt,
                                                        int2* __restrict__ stage, int e) {
    __shared__ int lcnt[512];
    __shared__ int lbase[512];
    int tid = threadIdx.x;
    for (int i = tid; i < 512; i += 256) lcnt[i] = 0;
    __syncthreads();
    int i0 = blockIdx.x * EPB;
    int cnt = min(EPB, e - i0);
    int s[16], d[16], rk[16];
    int nn = 0;
    for (int k = tid; k < cnt; k += 256) {
        s[nn] = src[i0 + k];
        d[nn] = dst[i0 + k];
        rk[nn] = atomicAdd(&lcnt[d[nn] >> 7], 1);
        nn++;
    }
    __syncthreads();
    for (int i = tid; i < 512; i += 256)
        lbase[i] = lcnt[i] ? atomicAdd(&bcnt[i], lcnt[i]) : 0;
    __syncthreads();
    for (int k = 0; k < nn; k++) {
        int b = d[k] >> 7;
        stage[(size_t)b * BCAP + lbase[b] + rk[k]] = make_int2(s[k], d[k]);
    }
}

// Pass 2: block b drains bucket b (nodes [b*128, b*128+128)); per-node cursors
// in LDS; csr writes land in a ~8KB contiguous region owned by this block.
__global__ __launch_bounds__(256) void bucket_to_csr_k(const int2* __restrict__ stage,
                                                       const int* __restrict__ bcnt,
                                                       const int* __restrict__ offs,
                                                       int* __restrict__ csr, int n) {
    __shared__ int wl[128];
    int b = blockIdx.x;
    int base = b << 7;
    int tid = threadIdx.x;
    if (tid < 128 && base + tid < n) wl[tid] = offs[base + tid];
    __syncthreads();
    int cnt = bcnt[b];
    for (int k = tid; k < cnt; k += 256) {
        int2 sd = stage[(size_t)b * BCAP + k];
        int slot = atomicAdd(&wl[sd.y & 127], 1);
        csr[slot] = sd.x;
    }
}

// GENConv softmax aggregation: one wave per node, lane = channel.
// Online softmax, 8-edge pipelined unroll (8 gathers in flight per wave).
__global__ __launch_bounds__(256) void conv_k(const float* __restrict__ h,
                                              const int* __restrict__ offs,
                                              const int* __restrict__ deg,
                                              const int* __restrict__ csr,
                                              const float* __restrict__ tptr,
                                              float* __restrict__ out, int n) {
    int wid = threadIdx.x >> 6, lane = threadIdx.x & 63;
    int node = blockIdx.x * 4 + wid;
    if (node >= n) return;
    float tt = tptr[0];
    int start = offs[node], d = deg[node];
    float m = -__builtin_huge_valf(), num = 0.f, den = 0.f;
    int i = 0;
    for (; i + 8 <= d; i += 8) {
        int sx[8];
        float v[8];
        #pragma unroll
        for (int q = 0; q < 8; q++) sx[q] = csr[start + i + q];
        #pragma unroll
        for (int q = 0; q < 8; q++) v[q] = h[(size_t)sx[q] * 64 + lane];
        float msg[8], w[8];
        float wm = m;
        #pragma unroll
        for (int q = 0; q < 8; q++) {
            msg[q] = fmaxf(v[q], 0.f) + 1e-7f;
            w[q] = msg[q] * tt;
            wm = fmaxf(wm, w[q]);
        }
        float sc = __expf(m - wm);
        num *= sc; den *= sc;
        #pragma unroll
        for (int q = 0; q < 8; q++) {
            float p = __expf(w[q] - wm);
            num += msg[q] * p;
            den += p;
        }
        m = wm;
    }
    for (; i + 4 <= d; i += 4) {
        int s0 = csr[start + i],     s1 = csr[start + i + 1];
        int s2 = csr[start + i + 2], s3 = csr[start + i + 3];
        float v0 = h[(size_t)s0 * 64 + lane];
        float v1 = h[(size_t)s1 * 64 + lane];
        float v2 = h[(size_t)s2 * 64 + lane];
        float v3 = h[(size_t)s3 * 64 + lane];
        float msg0 = fmaxf(v0, 0.f) + 1e-7f;
        float msg1 = fmaxf(v1, 0.f) + 1e-7f;
        float msg2 = fmaxf(v2, 0.f) + 1e-7f;
        float msg3 = fmaxf(v3, 0.f) + 1e-7f;
        float w0 = msg0 * tt, w1 = msg1 * tt, w2 = msg2 * tt, w3 = msg3 * tt;
        float nm = fmaxf(fmaxf(m, fmaxf(w0, w1)), fmaxf(w2, w3));
        float sc = __expf(m - nm);
        float p0 = __expf(w0 - nm), p1 = __expf(w1 - nm);
        float p2 = __expf(w2 - nm), p3 = __expf(w3 - nm);
        num = num * sc + (msg0 * p0 + msg1 * p1) + (msg2 * p2 + msg3 * p3);
        den = den * sc + (p0 + p1) + (p2 + p3);
        m = nm;
    }
    for (; i < d; i++) {
        int s0 = csr[start + i];
        float v0 = h[(size_t)s0 * 64 + lane];
        float msg0 = fmaxf(v0, 0.f) + 1e-7f;
        float w0 = msg0 * tt;
        float nm = fmaxf(m, w0);
        float sc = __expf(m - nm);
        float p0 = __expf(w0 - nm);
        num = num * sc + msg0 * p0;
        den = den * sc + p0;
        m = nm;
    }
    float agg = num / (den + 1e-16f);
    out[(size_t)node * 64 + lane] = agg + h[(size_t)node * 64 + lane];
}

__global__ __launch_bounds__(256) void ln_relu_k(const float* __restrict__ x,
                                                 const float* __restrict__ g,
                                                 const float* __restrict__ b,
                                                 float* __restrict__ out, int n) {
    int wid = threadIdx.x >> 6, lane = threadIdx.x & 63;
    int node = blockIdx.x * 4 + wid;
    if (node >= n) return;
    float v = x[(size_t)node * 64 + lane];
    float mu = wave_sum(v) * (1.f / 64.f);
    float d = v - mu;
    float var = wave_sum(d * d) * (1.f / 64.f);
    float r = d * rsqrtf(var + 1e-5f);
    out[(size_t)node * 64 + lane] = fmaxf(r * g[lane] + b[lane], 0.f);
}

// GEMM1 + LN + ReLU: r[node,0:128] = relu(LN(in[node,:] @ W1^T + b1))
// Lane owns output channels (lane, lane+64); W1 rows register-resident.
__global__ __launch_bounds__(256, 2) void mlp1_k(const float* __restrict__ in,
                                                 const float* __restrict__ W1,
                                                 const float* __restrict__ b1,
                                                 const float* __restrict__ mg,
                                                 const float* __restrict__ mb,
                                                 float* __restrict__ r, int n) {
    __shared__ float zs[4][64];
    int wid = threadIdx.x >> 6, lane = threadIdx.x & 63;

    const float4* W1v = (const float4*)W1;
    float4 wa[16], wb[16];
    #pragma unroll
    for (int q = 0; q < 16; q++) {
        wa[q] = W1v[lane * 16 + q];          // row `lane`   of W1 [128][64]
        wb[q] = W1v[(lane + 64) * 16 + q];   // row `lane+64`
    }
    float ba = b1[lane], bb = b1[lane + 64];
    float ga = mg[lane], gb = mg[lane + 64];
    float ca = mb[lane], cb = mb[lane + 64];

    for (int node = blockIdx.x * 4 + wid; node < n; node += gridDim.x * 4) {
        zs[wid][lane] = in[(size_t)node * 64 + lane];
        const float4* z4 = (const float4*)zs[wid];
        float ha = ba, hb = bb;
        #pragma unroll
        for (int q = 0; q < 16; q++) {
            float4 z = z4[q];                 // uniform-address broadcast read
            ha += wa[q].x * z.x + wa[q].y * z.y + wa[q].z * z.z + wa[q].w * z.w;
            hb += wb[q].x * z.x + wb[q].y * z.y + wb[q].z * z.z + wb[q].w * z.w;
        }
        float mu = wave_sum(ha + hb) * (1.f / 128.f);
        float da = ha - mu, db = hb - mu;
        float rstd = rsqrtf(wave_sum(da * da + db * db) * (1.f / 128.f) + 1e-5f);
        float ra = fmaxf(da * rstd * ga + ca, 0.f);
        float rb = fmaxf(db * rstd * gb + cb, 0.f);
        r[(size_t)node * 128 + lane] = ra;
        r[(size_t)node * 128 + 64 + lane] = rb;
    }
}

// GEMM2 (+bias, +optional residual): xout[node,lane] = r[node,:] @ W2[lane,:] + b2 (+xout)
template <int RES>
__global__ __launch_bounds__(256, 2) void mlp2_k(const float* __restrict__ r,
                                                 const float* __restrict__ W2,
                                                 const float* __restrict__ b2,
                                                 float* __restrict__ xio, int n) {
    __shared__ float rs[4][128];
    int wid = threadIdx.x >> 6, lane = threadIdx.x & 63;

    const float4* W2v = (const float4*)W2;
    float4 w[32];
    #pragma unroll
    for (int q = 0; q < 32; q++) w[q] = W2v[lane * 32 + q];   // row `lane` of W2 [64][128]
    float bz = b2[lane];

    for (int node = blockIdx.x * 4 + wid; node < n; node += gridDim.x * 4) {
        rs[wid][lane] = r[(size_t)node * 128 + lane];
        rs[wid][64 + lane] = r[(size_t)node * 128 + 64 + lane];
        const float4* r4 = (const float4*)rs[wid];
        float acc = bz;
        #pragma unroll
        for (int q = 0; q < 32; q++) {
            float4 v = r4[q];                 // uniform-address broadcast read
            acc += w[q].x * v.x + w[q].y * v.y + w[q].z * v.z + w[q].w * v.w;
        }
        if (RES) acc += xio[(size_t)node * 64 + lane];
        xio[(size_t)node * 64 + lane] = acc;
    }
}

extern "C" void kernel_launch(void* const* d_in, const int* in_sizes, int n_in,
                              void* d_out, int out_size, void* d_ws, size_t ws_size,
                              hipStream_t stream) {
    const float* x   = (const float*)d_in[0];
    const int*   ei  = (const int*)d_in[1];
    const float* t   = (const float*)d_in[2];
    const float* W1  = (const float*)d_in[3];
    const float* b1  = (const float*)d_in[4];
    const float* mg  = (const float*)d_in[5];
    const float* mb  = (const float*)d_in[6];
    const float* W2  = (const float*)d_in[7];
    const float* b2  = (const float*)d_in[8];
    const float* lng = (const float*)d_in[9];
    const float* lnb = (const float*)d_in[10];

    int n = in_sizes[0] / 64;
    int e = in_sizes[1] / 2;
    int L = in_sizes[2];
    const int* src = ei;
    const int* dst = ei + e;

    char* ws = (char*)d_ws;
    size_t off = 0;
    auto alloc = [&](size_t bytes) -> void* {
        void* p = ws + off;
        off = (off + bytes + 255) & ~(size_t)255;
        return p;
    };
    int*   degb  = (int*)alloc(((size_t)n + 512) * 4);   // deg[n] + bcnt[512]
    int*   deg   = degb;
    int*   bcnt  = degb + n;
    int*   offs  = (int*)alloc((size_t)n * 4);
    int*   bsum  = (int*)alloc(256 * 4);
    int*   bbase = (int*)alloc(256 * 4);
    int*   csr   = (int*)alloc((size_t)e * 4);
    float* xcur  = (float*)alloc((size_t)n * 64 * 4);
    float* hin   = (float*)alloc((size_t)n * 64 * 4);
    float* tmp   = (float*)alloc((size_t)n * 64 * 4);
    float* rbuf  = (float*)alloc((size_t)n * 128 * 4);   // also aliased as CSR staging
    int2*  stage = (int2*)rbuf;                          // 512*4096*8B = 16.8MB <= 25.6MB

    int nb = (n + 1023) / 1024;
    int nbuck = (n + 127) >> 7;
    zero_ints_k<<<(n + 512 + 255) / 256, 256, 0, stream>>>(degb, n + 512);
    hist_k<<<(e + 255) / 256, 256, 0, stream>>>(dst, deg, e);
    scan_block_k<<<nb, 1024, 0, stream>>>(deg, offs, bsum, n);
    scan_tops_k<<<1, 64, 0, stream>>>(bsum, bbase, nb);
    add_base_k<<<(n + 255) / 256, 256, 0, stream>>>(offs, bbase, n);
    bucket_scatter_k<<<(e + EPB - 1) / EPB, 256, 0, stream>>>(src, dst, bcnt, stage, e);
    bucket_to_csr_k<<<nbuck, 256, 0, stream>>>(stage, bcnt, offs, csr, n);

    int nodeBlocks = (n + 3) / 4;
    const int mlpGrid = 512;   // 2 blocks/CU; ~24 nodes/wave amortizes reg-weight load

    // layer 0: x = mlp(conv(x))  (no residual)
    conv_k<<<nodeBlocks, 256, 0, stream>>>(x, offs, deg, csr, t + 0, tmp, n);
    mlp1_k<<<mlpGrid, 256, 0, stream>>>(tmp, W1, b1, mg, mb, rbuf, n);
    mlp2_k<0><<<mlpGrid, 256, 0, stream>>>(rbuf, W2, b2, xcur, n);

    // layers 1..L-1: x = x + mlp(conv(relu(LN(x))))
    for (int i = 1; i < L; i++) {
        ln_relu_k<<<nodeBlocks, 256, 0, stream>>>(xcur, lng + i * 64, lnb + i * 64, hin, n);
        conv_k<<<nodeBlocks, 256, 0, stream>>>(hin, offs, deg, csr, t + i, tmp, n);
        mlp1_k<<<mlpGrid, 256, 0, stream>>>(tmp, W1 + (size_t)i * 8192, b1 + i * 128,
                                            mg + i * 128, mb + i * 128, rbuf, n);
        mlp2_k<1><<<mlpGrid, 256, 0, stream>>>(rbuf, W2 + (size_t)i * 8192, b2 + i * 64, xcur, n);
    }

    // final: relu(LN(x, lng[0], lnb[0])) -> d_out
    ln_relu_k<<<nodeBlocks, 256, 0, stream>>>(xcur, lng, lnb, (float*)d_out, n);
}

// Round 7
// 559.733 us; speedup vs baseline: 1.8779x; 1.0762x over previous
//
#include <hip/hip_runtime.h>
#include <hip/hip_bf16.h>

// DeeperGCN (GENConv softmax-agg) on MI355X.
// R7: 15 dispatches (was 24). CSR: zero+scatter+bucket_to_csr(local scan,
// bucket-contiguous). LN+ReLU fused into mlp2 (wave holds full row).

static __device__ __forceinline__ float wave_sum(float v) {
    #pragma unroll
    for (int o = 32; o; o >>= 1) v += __shfl_xor(v, o);
    return v;
}

#define EPB 4096
#define BCAP 4096

__global__ void zero_bcnt_k(int* __restrict__ p) { p[threadIdx.x] = 0; }

// Pass 1: block ranks 4096 contiguous edges per 128-node bucket via LDS
// atomics (ranks kept in LDS, not scratch), reserves per-bucket global ranges
// (<=512 global atomics/block), appends (src,dst) line-locally into staging.
__global__ __launch_bounds__(256) void bucket_scatter_k(const int* __restrict__ src,
                                                        const int* __restrict__ dst,
                                                        int* __restrict__ bcnt,
                                                        int2* __restrict__ stage, int e) {
    __shared__ int lcnt[512];
    __shared__ int lbase[512];
    __shared__ int rkbuf[EPB];
    int tid = threadIdx.x;
    for (int i = tid; i < 512; i += 256) lcnt[i] = 0;
    __syncthreads();
    int i0 = blockIdx.x * EPB;
    int cnt = min(EPB, e - i0);
    for (int k = tid; k < cnt; k += 256) {
        int d = dst[i0 + k];
        rkbuf[k] = atomicAdd(&lcnt[d >> 7], 1);
    }
    __syncthreads();
    for (int i = tid; i < 512; i += 256)
        lbase[i] = lcnt[i] ? atomicAdd(&bcnt[i], lcnt[i]) : 0;
    __syncthreads();
    for (int k = tid; k < cnt; k += 256) {
        int s = src[i0 + k];
        int d = dst[i0 + k];
        int b = d >> 7;
        stage[(size_t)b * BCAP + lbase[b] + rkbuf[k]] = make_int2(s, d);
    }
}

// Pass 2: block b drains bucket b; 128-node LDS histogram + scan gives local
// offsets; emits bucket-contiguous CSR plus offs[] and deg[] (no global scan).
__global__ __launch_bounds__(256) void bucket_to_csr_k(const int2* __restrict__ stage,
                                                       const int* __restrict__ bcnt,
                                                       int* __restrict__ csr,
                                                       int* __restrict__ offs,
                                                       int* __restrict__ deg, int n) {
    __shared__ int lcnt[128];
    __shared__ int loff[128];
    __shared__ int wl[128];
    int b = blockIdx.x;
    int tid = threadIdx.x;
    int base = b << 7;
    if (tid < 128) lcnt[tid] = 0;
    __syncthreads();
    int cnt = bcnt[b];
    const int2* sb = stage + (size_t)b * BCAP;
    for (int k = tid; k < cnt; k += 256)
        atomicAdd(&lcnt[sb[k].y & 127], 1);
    __syncthreads();
    if (tid < 128) loff[tid] = lcnt[tid];
    __syncthreads();
    #pragma unroll
    for (int o = 1; o < 128; o <<= 1) {
        int v = 0;
        if (tid < 128 && tid >= o) v = loff[tid - o];
        __syncthreads();
        if (tid < 128) loff[tid] += v;
        __syncthreads();
    }
    if (tid < 128) {
        int ex = loff[tid] - lcnt[tid];          // exclusive scan
        wl[tid] = ex;
        if (base + tid < n) {
            offs[base + tid] = b * BCAP + ex;
            deg[base + tid] = lcnt[tid];
        }
    }
    __syncthreads();
    for (int k = tid; k < cnt; k += 256) {
        int2 sd = sb[k];
        int slot = atomicAdd(&wl[sd.y & 127], 1);
        csr[(size_t)b * BCAP + slot] = sd.x;
    }
}

// GENConv softmax aggregation: one wave per node, lane = channel.
// Online softmax, 8-edge pipelined unroll (8 gathers in flight per wave).
__global__ __launch_bounds__(256) void conv_k(const float* __restrict__ h,
                                              const int* __restrict__ offs,
                                              const int* __restrict__ deg,
                                              const int* __restrict__ csr,
                                              const float* __restrict__ tptr,
                                              float* __restrict__ out, int n) {
    int wid = threadIdx.x >> 6, lane = threadIdx.x & 63;
    int node = blockIdx.x * 4 + wid;
    if (node >= n) return;
    float tt = tptr[0];
    int start = offs[node], d = deg[node];
    float m = -__builtin_huge_valf(), num = 0.f, den = 0.f;
    int i = 0;
    for (; i + 8 <= d; i += 8) {
        int sx[8];
        float v[8];
        #pragma unroll
        for (int q = 0; q < 8; q++) sx[q] = csr[start + i + q];
        #pragma unroll
        for (int q = 0; q < 8; q++) v[q] = h[(size_t)sx[q] * 64 + lane];
        float msg[8], w[8];
        float wm = m;
        #pragma unroll
        for (int q = 0; q < 8; q++) {
            msg[q] = fmaxf(v[q], 0.f) + 1e-7f;
            w[q] = msg[q] * tt;
            wm = fmaxf(wm, w[q]);
        }
        float sc = __expf(m - wm);
        num *= sc; den *= sc;
        #pragma unroll
        for (int q = 0; q < 8; q++) {
            float p = __expf(w[q] - wm);
            num += msg[q] * p;
            den += p;
        }
        m = wm;
    }
    for (; i + 4 <= d; i += 4) {
        int s0 = csr[start + i],     s1 = csr[start + i + 1];
        int s2 = csr[start + i + 2], s3 = csr[start + i + 3];
        float v0 = h[(size_t)s0 * 64 + lane];
        float v1 = h[(size_t)s1 * 64 + lane];
        float v2 = h[(size_t)s2 * 64 + lane];
        float v3 = h[(size_t)s3 * 64 + lane];
        float msg0 = fmaxf(v0, 0.f) + 1e-7f;
        float msg1 = fmaxf(v1, 0.f) + 1e-7f;
        float msg2 = fmaxf(v2, 0.f) + 1e-7f;
        float msg3 = fmaxf(v3, 0.f) + 1e-7f;
        float w0 = msg0 * tt, w1 = msg1 * tt, w2 = msg2 * tt, w3 = msg3 * tt;
        float nm = fmaxf(fmaxf(m, fmaxf(w0, w1)), fmaxf(w2, w3));
        float sc = __expf(m - nm);
        float p0 = __expf(w0 - nm), p1 = __expf(w1 - nm);
        float p2 = __expf(w2 - nm), p3 = __expf(w3 - nm);
        num = num * sc + (msg0 * p0 + msg1 * p1) + (msg2 * p2 + msg3 * p3);
        den = den * sc + (p0 + p1) + (p2 + p3);
        m = nm;
    }
    for (; i < d; i++) {
        int s0 = csr[start + i];
        float v0 = h[(size_t)s0 * 64 + lane];
        float msg0 = fmaxf(v0, 0.f) + 1e-7f;
        float w0 = msg0 * tt;
        float nm = fmaxf(m, w0);
        float sc = __expf(m - nm);
        float p0 = __expf(w0 - nm);
        num = num * sc + msg0 * p0;
        den = den * sc + p0;
        m = nm;
    }
    float agg = num / (den + 1e-16f);
    out[(size_t)node * 64 + lane] = agg + h[(size_t)node * 64 + lane];
}

// GEMM1 + LN + ReLU: r[node,0:128] = relu(LN(in[node,:] @ W1^T + b1))
// Lane owns output channels (lane, lane+64); W1 rows register-resident.
__global__ __launch_bounds__(256, 2) void mlp1_k(const float* __restrict__ in,
                                                 const float* __restrict__ W1,
                                                 const float* __restrict__ b1,
                                                 const float* __restrict__ mg,
                                                 const float* __restrict__ mb,
                                                 float* __restrict__ r, int n) {
    __shared__ float zs[4][64];
    int wid = threadIdx.x >> 6, lane = threadIdx.x & 63;

    const float4* W1v = (const float4*)W1;
    float4 wa[16], wb[16];
    #pragma unroll
    for (int q = 0; q < 16; q++) {
        wa[q] = W1v[lane * 16 + q];          // row `lane`   of W1 [128][64]
        wb[q] = W1v[(lane + 64) * 16 + q];   // row `lane+64`
    }
    float ba = b1[lane], bb = b1[lane + 64];
    float ga = mg[lane], gb = mg[lane + 64];
    float ca = mb[lane], cb = mb[lane + 64];

    for (int node = blockIdx.x * 4 + wid; node < n; node += gridDim.x * 4) {
        zs[wid][lane] = in[(size_t)node * 64 + lane];
        const float4* z4 = (const float4*)zs[wid];
        float ha = ba, hb = bb;
        #pragma unroll
        for (int q = 0; q < 16; q++) {
            float4 z = z4[q];                 // uniform-address broadcast read
            ha += wa[q].x * z.x + wa[q].y * z.y + wa[q].z * z.z + wa[q].w * z.w;
            hb += wb[q].x * z.x + wb[q].y * z.y + wb[q].z * z.z + wb[q].w * z.w;
        }
        float mu = wave_sum(ha + hb) * (1.f / 128.f);
        float da = ha - mu, db = hb - mu;
        float rstd = rsqrtf(wave_sum(da * da + db * db) * (1.f / 128.f) + 1e-5f);
        float ra = fmaxf(da * rstd * ga + ca, 0.f);
        float rb = fmaxf(db * rstd * gb + cb, 0.f);
        r[(size_t)node * 128 + lane] = ra;
        r[(size_t)node * 128 + 64 + lane] = rb;
    }
}

// GEMM2 + bias (+residual) + fused next-LN+ReLU.
// Wave holds the complete 64-ch output row -> LN via wave reductions.
// WX: also store x_new (skipped for the final layer, which writes only d_out).
template <int RES, int WX>
__global__ __launch_bounds__(256, 2) void mlp2ln_k(const float* __restrict__ r,
                                                   const float* __restrict__ W2,
                                                   const float* __restrict__ b2,
                                                   const float* __restrict__ g,
                                                   const float* __restrict__ bb,
                                                   float* __restrict__ xio,
                                                   float* __restrict__ hout, int n) {
    __shared__ float rs[4][128];
    int wid = threadIdx.x >> 6, lane = threadIdx.x & 63;

    const float4* W2v = (const float4*)W2;
    float4 w[32];
    #pragma unroll
    for (int q = 0; q < 32; q++) w[q] = W2v[lane * 32 + q];   // row `lane` of W2 [64][128]
    float bz = b2[lane];
    float gl = g[lane], bl = bb[lane];

    for (int node = blockIdx.x * 4 + wid; node < n; node += gridDim.x * 4) {
        float res = 0.f;
        if (RES) res = xio[(size_t)node * 64 + lane];          // issue early
        rs[wid][lane] = r[(size_t)node * 128 + lane];
        rs[wid][64 + lane] = r[(size_t)node * 128 + 64 + lane];
        const float4* r4 = (const float4*)rs[wid];
        float acc = bz;
        #pragma unroll
        for (int q = 0; q < 32; q++) {
            float4 v = r4[q];                 // uniform-address broadcast read
            acc += w[q].x * v.x + w[q].y * v.y + w[q].z * v.z + w[q].w * v.w;
        }
        if (RES) acc += res;
        if (WX) xio[(size_t)node * 64 + lane] = acc;
        float mu = wave_sum(acc) * (1.f / 64.f);
        float dv = acc - mu;
        float var = wave_sum(dv * dv) * (1.f / 64.f);
        float rr = dv * rsqrtf(var + 1e-5f);
        hout[(size_t)node * 64 + lane] = fmaxf(rr * gl + bl, 0.f);
    }
}

extern "C" void kernel_launch(void* const* d_in, const int* in_sizes, int n_in,
                              void* d_out, int out_size, void* d_ws, size_t ws_size,
                              hipStream_t stream) {
    const float* x   = (const float*)d_in[0];
    const int*   ei  = (const int*)d_in[1];
    const float* t   = (const float*)d_in[2];
    const float* W1  = (const float*)d_in[3];
    const float* b1  = (const float*)d_in[4];
    const float* mg  = (const float*)d_in[5];
    const float* mb  = (const float*)d_in[6];
    const float* W2  = (const float*)d_in[7];
    const float* b2  = (const float*)d_in[8];
    const float* lng = (const float*)d_in[9];
    const float* lnb = (const float*)d_in[10];

    int n = in_sizes[0] / 64;
    int e = in_sizes[1] / 2;
    const int* src = ei;
    const int* dst = ei + e;

    char* ws = (char*)d_ws;
    size_t off = 0;
    auto alloc = [&](size_t bytes) -> void* {
        void* p = ws + off;
        off = (off + bytes + 255) & ~(size_t)255;
        return p;
    };
    int*   bcnt  = (int*)alloc(512 * 4);
    int*   offs  = (int*)alloc((size_t)n * 4);
    int*   deg   = (int*)alloc((size_t)n * 4);
    int*   csr   = (int*)alloc((size_t)512 * BCAP * 4);      // bucket-contiguous, 8.4MB
    float* xcur  = (float*)alloc((size_t)n * 64 * 4);
    float* hin   = (float*)alloc((size_t)n * 64 * 4);
    float* tmp   = (float*)alloc((size_t)n * 64 * 4);
    float* rbuf  = (float*)alloc((size_t)n * 128 * 4);
    int2*  stage = (int2*)rbuf;   // 512*4096*8B = 16.8MB, consumed before rbuf is written

    int nbuck = (n + 127) >> 7;
    zero_bcnt_k<<<1, 512, 0, stream>>>(bcnt);
    bucket_scatter_k<<<(e + EPB - 1) / EPB, 256, 0, stream>>>(src, dst, bcnt, stage, e);
    bucket_to_csr_k<<<nbuck, 256, 0, stream>>>(stage, bcnt, csr, offs, deg, n);

    int nodeBlocks = (n + 3) / 4;
    const int mlpGrid = 512;

    // layer 0: x = mlp(conv(x)); hin = relu(LN_1(x))
    conv_k<<<nodeBlocks, 256, 0, stream>>>(x, offs, deg, csr, t + 0, tmp, n);
    mlp1_k<<<mlpGrid, 256, 0, stream>>>(tmp, W1, b1, mg, mb, rbuf, n);
    mlp2ln_k<0, 1><<<mlpGrid, 256, 0, stream>>>(rbuf, W2, b2, lng + 64, lnb + 64,
                                                xcur, hin, n);
    // layers 1..2: x += mlp(conv(hin)); hin = relu(LN_{i+1}(x))
    for (int i = 1; i <= 2; i++) {
        conv_k<<<nodeBlocks, 256, 0, stream>>>(hin, offs, deg, csr, t + i, tmp, n);
        mlp1_k<<<mlpGrid, 256, 0, stream>>>(tmp, W1 + (size_t)i * 8192, b1 + i * 128,
                                            mg + i * 128, mb + i * 128, rbuf, n);
        mlp2ln_k<1, 1><<<mlpGrid, 256, 0, stream>>>(rbuf, W2 + (size_t)i * 8192, b2 + i * 64,
                                                    lng + (i + 1) * 64, lnb + (i + 1) * 64,
                                                    xcur, hin, n);
    }
    // layer 3: x += mlp(conv(hin)); d_out = relu(LN_0(x))  (x itself not stored)
    conv_k<<<nodeBlocks, 256, 0, stream>>>(hin, offs, deg, csr, t + 3, tmp, n);
    mlp1_k<<<mlpGrid, 256, 0, stream>>>(tmp, W1 + (size_t)3 * 8192, b1 + 3 * 128,
                                        mg + 3 * 128, mb + 3 * 128, rbuf, n);
    mlp2ln_k<1, 0><<<mlpGrid, 256, 0, stream>>>(rbuf, W2 + (size_t)3 * 8192, b2 + 3 * 64,
                                                lng, lnb, xcur, (float*)d_out, n);
}